// Round 12
// baseline (157.157 us; speedup 1.0000x reference)
//
#include <hip/hip_runtime.h>
#include <math.h>

#define B_  4
#define S_  1024
#define D_  512
#define H_  8
#define DK_ 64
#define P_  2047   // 2*S-1
#define MB_ (1u << 20)

typedef __bf16 bf16x8 __attribute__((ext_vector_type(8)));
typedef __bf16 bf16x4 __attribute__((ext_vector_type(4)));
typedef __bf16 bf16x2 __attribute__((ext_vector_type(2)));
typedef float  f32x4  __attribute__((ext_vector_type(4)));

__device__ __forceinline__ void cp16_g2l(const void* g, void* l) {
    __builtin_amdgcn_global_load_lds(
        (const __attribute__((address_space(1))) void*)g,
        (__attribute__((address_space(3))) void*)l, 16, 0, 0);
}

// ---------------- prep: LN + pos-emb + weight convert, fused ----------------
// blocks [0,1024): LayerNorm; [1024,3072): pe; [3072,3328): weight convert
__global__ __launch_bounds__(256) void prep_kernel(
        const float* __restrict__ x, const float* __restrict__ gamma,
        const float* __restrict__ beta,
        const float* __restrict__ Wq, const float* __restrict__ Wk,
        const float* __restrict__ Wv, const float* __restrict__ Wp,
        const float* __restrict__ Wo, const float* __restrict__ bq,
        const float* __restrict__ bk, const float* __restrict__ bv,
        __bf16* __restrict__ xh, __bf16* __restrict__ peh,
        __bf16* __restrict__ Wqkv, __bf16* __restrict__ Wpb,
        __bf16* __restrict__ Wob, float* __restrict__ biasqkv) {
    const int bid = blockIdx.x;
    const int t   = threadIdx.x;
    if (bid < 1024) {
        const int wave = t >> 6;
        const int lane = t & 63;
        const int row  = bid * 4 + wave;
        const float* xr = x + (size_t)row * D_;
        const int d0 = lane * 4;
        float4 a = *(const float4*)(xr + d0);
        float4 c = *(const float4*)(xr + d0 + 256);
        float s  = a.x + a.y + a.z + a.w + c.x + c.y + c.z + c.w;
        float ss = a.x*a.x + a.y*a.y + a.z*a.z + a.w*a.w
                 + c.x*c.x + c.y*c.y + c.z*c.z + c.w*c.w;
        #pragma unroll
        for (int off = 32; off > 0; off >>= 1) {
            s  += __shfl_xor(s, off);
            ss += __shfl_xor(ss, off);
        }
        const float mu   = s * (1.0f / D_);
        const float var  = ss * (1.0f / D_) - mu * mu;
        const float rstd = rsqrtf(var + 1e-5f);
        #pragma unroll
        for (int half = 0; half < 2; ++half) {
            const int dd = d0 + half * 256;
            float4 xv = half ? c : a;
            float4 g  = *(const float4*)(gamma + dd);
            float4 be = *(const float4*)(beta + dd);
            bf16x4 hv;
            hv[0] = (__bf16)((xv.x - mu) * rstd * g.x + be.x);
            hv[1] = (__bf16)((xv.y - mu) * rstd * g.y + be.y);
            hv[2] = (__bf16)((xv.z - mu) * rstd * g.z + be.z);
            hv[3] = (__bf16)((xv.w - mu) * rstd * g.w + be.w);
            *(bf16x4*)(xh + (size_t)row * D_ + dd) = hv;
        }
    } else if (bid < 3072) {
        const int pos = bid - 1024;        // 0..2047
        const int j   = t;                 // 0..255
        union { __bf16 b[2]; unsigned u; } ph;
        if (pos >= P_) {
            ph.u = 0u;
        } else {
            const float posv = (float)(pos - (S_ - 1));
            const float div = __expf((float)(2 * j) * (-0.017988946039015984f));
            const float ang = posv * div;
            float sv, cv;
            __sincosf(ang, &sv, &cv);
            ph.b[0] = (__bf16)sv;  ph.b[1] = (__bf16)cv;
        }
        ((unsigned*)peh)[(size_t)pos * 256 + j] = ph.u;
    } else {
        const int idx = (bid - 3072) * 256 + t;   // 0..65535
        #pragma unroll
        for (int r = 0; r < 4; ++r) {
            const int i = idx + r * 65536;        // 0..262143
            Wqkv[i]          = (__bf16)Wq[i];
            Wqkv[i + 262144] = (__bf16)Wk[i];
            Wqkv[i + 524288] = (__bf16)Wv[i];
            Wpb[i]           = (__bf16)Wp[i];
            Wob[i]           = (__bf16)Wo[i];
        }
        if (idx < 512) {
            biasqkv[idx]        = bq[idx];
            biasqkv[idx + 512]  = bk[idx];
            biasqkv[idx + 1024] = bv[idx];
        }
    }
}

// -------- bf16 MFMA GEMM body, double-buffered single-barrier K-loop --------
struct GemmSmem {
    __bf16 A[2][128 * 32];
    __bf16 B[2][128 * 32];
};

// mode 0: qkv fused (N=1536): q/k (B,H,S,DK), v -> V^T packed
// mode 1: plain bf16 M x 512 (p-projection)
__device__ __forceinline__ void gemm_body(GemmSmem& sm,
        const __bf16* __restrict__ Ab, const __bf16* __restrict__ Bw,
        const float* __restrict__ bias, int row0, int col0, int mode,
        void* __restrict__ C0, void* __restrict__ C1, void* __restrict__ C2) {
    const int t    = threadIdx.x;
    const int w    = t >> 6;
    const int lane = t & 63;
    const int col  = lane & 15;
    const int grp  = lane >> 4;
    const int wm   = w >> 1;
    const int wn   = w & 1;
    const int l4r  = lane >> 2;
    const int l4c  = lane & 3;

    f32x4 acc[4][4] = {};

    #define GSTAGE(kt_, sb_)                                                   \
        {                                                                      \
            const int k0s = (kt_) * 32;                                        \
            _Pragma("unroll")                                                  \
            for (int tt = 0; tt < 2; ++tt) {                                   \
                const int row = w * 32 + tt * 16 + l4r;                        \
                const int gc  = l4c ^ ((row >> 1) & 3);                        \
                const int cb  = (w * 32 + tt * 16) * 32;                       \
                cp16_g2l(Ab + (size_t)(row0 + row) * 512 + k0s + gc * 8,       \
                         &sm.A[sb_][cb]);                                      \
                cp16_g2l(Bw + (size_t)(col0 + row) * 512 + k0s + gc * 8,       \
                         &sm.B[sb_][cb]);                                      \
            }                                                                  \
        }

    GSTAGE(0, 0);
    for (int kt = 0; kt < 16; ++kt) {
        __syncthreads();                  // drains buf[kt&1] loads (issued kt-1)
        if (kt < 15) GSTAGE(kt + 1, (kt + 1) & 1);   // flies during compute
        const int cbuf = kt & 1;
        bf16x8 fa[4], fb[4];
        #pragma unroll
        for (int i = 0; i < 4; ++i) {
            const int ar = wm * 64 + i * 16 + col;
            const int ac = (grp ^ ((ar >> 1) & 3)) * 8;
            fa[i] = *(const bf16x8*)&sm.A[cbuf][ar * 32 + ac];
            const int br = wn * 64 + i * 16 + col;
            const int bc = (grp ^ ((br >> 1) & 3)) * 8;
            fb[i] = *(const bf16x8*)&sm.B[cbuf][br * 32 + bc];
        }
        #pragma unroll
        for (int mi = 0; mi < 4; ++mi)
            #pragma unroll
            for (int ni = 0; ni < 4; ++ni)
                acc[mi][ni] = __builtin_amdgcn_mfma_f32_16x16x32_bf16(fa[mi], fb[ni], acc[mi][ni], 0, 0, 0);
    }
    #undef GSTAGE

    #pragma unroll
    for (int mi = 0; mi < 4; ++mi) {
        const int rbase = row0 + wm * 64 + mi * 16 + grp * 4;
        #pragma unroll
        for (int ni = 0; ni < 4; ++ni) {
            const int c = col0 + wn * 64 + ni * 16 + col;
            if (mode == 0) {
                const int proj = c >> 9, wc = c & 511;
                const int hh = wc >> 6, dk = wc & 63;
                const int bb2 = rbase >> 10, ss = rbase & 1023;
                const float bc = bias[c];
                if (proj == 2) {
                    bf16x4 pack;
                    #pragma unroll
                    for (int reg = 0; reg < 4; ++reg)
                        pack[reg] = (__bf16)(acc[mi][ni][reg] + bc);
                    *(bf16x4*)&((__bf16*)C2)[(((size_t)bb2 * H_ + hh) * DK_ + dk) * S_ + ss] = pack;
                } else {
                    __bf16* dst = proj ? (__bf16*)C1 : (__bf16*)C0;
                    #pragma unroll
                    for (int reg = 0; reg < 4; ++reg)
                        dst[((((size_t)bb2 * H_ + hh) << 10) + ss + reg) * DK_ + dk] =
                            (__bf16)(acc[mi][ni][reg] + bc);
                }
            } else {
                #pragma unroll
                for (int reg = 0; reg < 4; ++reg)
                    ((__bf16*)C0)[(size_t)(rbase + reg) * 512 + c] = (__bf16)acc[mi][ni][reg];
            }
        }
    }
}

// fused qkv (384 blocks) + p-projection (64 blocks)
__global__ __launch_bounds__(256) void gemm_qkv_p(
        const __bf16* __restrict__ xh, const __bf16* __restrict__ Wqkv,
        const float* __restrict__ biasqkv,
        const __bf16* __restrict__ peh, const __bf16* __restrict__ Wpb,
        __bf16* __restrict__ qb, __bf16* __restrict__ kb,
        __bf16* __restrict__ vt, __bf16* __restrict__ pp) {
    __shared__ __align__(16) GemmSmem sm;
    const int bid = blockIdx.x;
    if (bid < 384) {
        gemm_body(sm, xh, Wqkv, biasqkv, (bid & 31) * 128, (bid >> 5) * 128,
                  0, qb, kb, vt);
    } else {
        const int pid = bid - 384;
        gemm_body(sm, peh, Wpb, nullptr, (pid & 15) * 128, (pid >> 4) * 128,
                  1, pp, nullptr, nullptr);
    }
}

// ---- output GEMM: 64x128 tiles, 256 blocks, dbuf pipelined, fp32 out ------
struct Gemm64Smem {
    __bf16 A[2][64 * 32];
    __bf16 B[2][128 * 32];
};

__global__ __launch_bounds__(256) void gemm_out64(
        const __bf16* __restrict__ ch, const __bf16* __restrict__ Wob,
        const float* __restrict__ bo, float* __restrict__ out) {
    __shared__ __align__(16) Gemm64Smem sm;
    const int row0 = (int)(blockIdx.x & 63) * 64;
    const int col0 = (int)(blockIdx.x >> 6) * 128;
    const int t    = threadIdx.x;
    const int w    = t >> 6;
    const int lane = t & 63;
    const int col  = lane & 15;
    const int grp  = lane >> 4;
    const int wm   = w >> 1;
    const int wn   = w & 1;

    f32x4 acc[2][4] = {};

    #define OSTAGE(kt_, sb_)                                                   \
        {                                                                      \
            const int k0s = (kt_) * 32;                                        \
            const int rA = w * 16 + (lane >> 2);                               \
            const int cA = (lane & 3) ^ ((rA >> 1) & 3);                       \
            cp16_g2l(ch + (size_t)(row0 + rA) * 512 + k0s + cA * 8,            \
                     &sm.A[sb_][w * 16 * 32]);                                 \
            _Pragma("unroll")                                                  \
            for (int ps = 0; ps < 2; ++ps) {                                   \
                const int rB = ps * 64 + w * 16 + (lane >> 2);                 \
                const int cB = (lane & 3) ^ ((rB >> 1) & 3);                   \
                cp16_g2l(Wob + (size_t)(col0 + rB) * 512 + k0s + cB * 8,       \
                         &sm.B[sb_][(ps * 64 + w * 16) * 32]);                 \
            }                                                                  \
        }

    OSTAGE(0, 0);
    for (int kt = 0; kt < 16; ++kt) {
        __syncthreads();
        if (kt < 15) OSTAGE(kt + 1, (kt + 1) & 1);
        const int cbuf = kt & 1;
        bf16x8 fa[2], fb[4];
        #pragma unroll
        for (int i = 0; i < 2; ++i) {
            const int ar = wm * 32 + i * 16 + col;
            const int ac = (grp ^ ((ar >> 1) & 3)) * 8;
            fa[i] = *(const bf16x8*)&sm.A[cbuf][ar * 32 + ac];
        }
        #pragma unroll
        for (int j = 0; j < 4; ++j) {
            const int br = wn * 64 + j * 16 + col;
            const int bc = (grp ^ ((br >> 1) & 3)) * 8;
            fb[j] = *(const bf16x8*)&sm.B[cbuf][br * 32 + bc];
        }
        #pragma unroll
        for (int i = 0; i < 2; ++i)
            #pragma unroll
            for (int j = 0; j < 4; ++j)
                acc[i][j] = __builtin_amdgcn_mfma_f32_16x16x32_bf16(fa[i], fb[j], acc[i][j], 0, 0, 0);
    }
    #undef OSTAGE

    #pragma unroll
    for (int i = 0; i < 2; ++i) {
        const int rbase = row0 + wm * 32 + i * 16 + grp * 4;
        #pragma unroll
        for (int j = 0; j < 4; ++j) {
            const int c = col0 + wn * 64 + j * 16 + col;
            const float bc = bo[c];
            #pragma unroll
            for (int reg = 0; reg < 4; ++reg)
                out[(size_t)(rbase + reg) * 512 + c] = acc[i][j][reg] + bc;
        }
    }
}

// ---------------- MFMA flash rel-pos attention (round-5 geometry) ----------
// 64 q-rows/block, 4 waves x 16 rows, k-split x2, grid 1024, 40KB LDS ->
// 4 blocks/CU (TLP hides barrier drains better than 128-row/2-block variants:
// measured 42.9 vs 45.3 us). No-max softmax; packed-f16 single-shuffle band
// select. scores[q][k] = ((q+u).k + (q+v).p[k-q+S])/8; wrap fix at (0,S-1).
__global__ __launch_bounds__(256, 4) void attn_mfma(
        const __bf16* __restrict__ qg, const __bf16* __restrict__ kg,
        const __bf16* __restrict__ vtg, const __bf16* __restrict__ pg,
        const float* __restrict__ pu, const float* __restrict__ pvb,
        float* __restrict__ Opart, float* __restrict__ lpart) {
    const int qb = blockIdx.x >> 1;
    const int kc = blockIdx.x & 1;
    const int q0 = qb * 64;
    const int h  = blockIdx.y;
    const int b  = blockIdx.z;
    const int t  = threadIdx.x;
    const int w    = t >> 6;
    const int lane = t & 63;
    const int col  = lane & 15;
    const int grp  = lane >> 4;
    const int swz  = col & 7;

    __shared__ __align__(16) __bf16 Klds[4096];      // K[kpos][dk]   swizzled
    __shared__ __align__(16) __bf16 Vtlds[4096];     // V^T[dk][kpos] swizzled
    __shared__ __align__(16) __bf16 Plds[8192];      // P window, 128 rows
    __shared__ __align__(16) __bf16 probs[4][1024];  // per-wave 16x64

    const size_t bh = (size_t)(b * H_ + h);
    const __bf16* qbh  = qg + bh * S_ * DK_;
    const __bf16* kbh  = kg + bh * S_ * DK_;
    const __bf16* vtbh = vtg + bh * DK_ * S_;

    // Q fragments (A-layout), 1 frag x 2 dk-halves
    bf16x8 qu_f[2], qv_f[2];
    {
        const int qrow = q0 + w * 16 + col;
        #pragma unroll
        for (int hf = 0; hf < 2; ++hf) {
            const int doff = hf * 32 + grp * 8;
            bf16x8 q8 = *(const bf16x8*)(qbh + (size_t)qrow * DK_ + doff);
            #pragma unroll
            for (int j = 0; j < 8; ++j) {
                const float qf = (float)q8[j];
                qu_f[hf][j] = (__bf16)(qf + pu [h * DK_ + doff + j]);
                qv_f[hf][j] = (__bf16)(qf + pvb[h * DK_ + doff + j]);
            }
        }
    }

    // rel_shift wrap fix: (q_1 + v) . p[0], used only at (q=0, k=S-1)
    const bool isfix = (q0 == 0 && kc == 1 && w == 0);
    float fix = 0.f;
    if (isfix) {
        for (int d = 0; d < 64; ++d)
            fix += ((float)qbh[DK_ + d] + pvb[h * DK_ + d]) * (float)pg[(size_t)h * DK_ + d];
    }

    f32x4 acc_o[4] = {};
    float l_acc[4] = {0.f, 0.f, 0.f, 0.f};

    const int n0w = 48 - 16 * w;         // wave's BD window start within Plds
    const int sr  = t >> 3;              // staging row 0..31
    const int c8  = t & 7;
    const int gc8 = (c8 ^ (sr & 7)) * 8; // swizzled global chunk (elems)
    __bf16* pw = probs[w];

    for (int kt = 0; kt < 8; ++kt) {
        const int k0 = kt * 64 + kc * 512;
        const int pbase = k0 - q0 - 63 + S_;   // >= 1 always
        __syncthreads();
        {
            const __bf16* kbase = kbh + (size_t)k0 * DK_;
            cp16_g2l(kbase + (size_t)sr * 64 + gc8,        &Klds[t * 8]);
            cp16_g2l(kbase + (size_t)(sr + 32) * 64 + gc8, &Klds[t * 8 + 2048]);
            const __bf16* vtb = vtbh + k0;
            cp16_g2l(vtb + (size_t)sr * S_ + gc8,          &Vtlds[t * 8]);
            cp16_g2l(vtb + (size_t)(sr + 32) * S_ + gc8,   &Vtlds[t * 8 + 2048]);
            const __bf16* pb = pg + (size_t)pbase * D_ + h * DK_;
            #pragma unroll
            for (int ps = 0; ps < 4; ++ps)
                cp16_g2l(pb + (size_t)(sr + ps * 32) * D_ + gc8,
                         &Plds[t * 8 + ps * 2048]);
        }
        __syncthreads();

        // AC = Qu . K^T
        f32x4 acc_ac[4] = {};
        #pragma unroll
        for (int tile = 0; tile < 4; ++tile) {
            const int rw = tile * 16 + col;
            #pragma unroll
            for (int hf = 0; hf < 2; ++hf) {
                bf16x8 bfr = *(const bf16x8*)&Klds[rw * 64 + ((hf * 4 + grp) ^ swz) * 8];
                acc_ac[tile] = __builtin_amdgcn_mfma_f32_16x16x32_bf16(qu_f[hf], bfr, acc_ac[tile], 0, 0, 0);
            }
        }
        // BD = Qv . P^T over 80-wide window
        f32x4 acc_bd[5] = {};
        #pragma unroll
        for (int tile = 0; tile < 5; ++tile) {
            const int rw = n0w + tile * 16 + col;
            #pragma unroll
            for (int hf = 0; hf < 2; ++hf) {
                bf16x8 bfr = *(const bf16x8*)&Plds[rw * 64 + ((hf * 4 + grp) ^ swz) * 8];
                acc_bd[tile] = __builtin_amdgcn_mfma_f32_16x16x32_bf16(qv_f[hf], bfr, acc_bd[tile], 0, 0, 0);
            }
        }
        // band select (packed-f16 single shuffle) + exp + l + probs store
        #pragma unroll
        for (int reg = 0; reg < 4; ++reg) {
            const int rr = grp * 4 + reg;
            const int cc = col + 15 - rr;            // 0..30
            const int srcl = (grp << 4) | (cc & 15);
            const bool lo = (cc < 16);
            #pragma unroll
            for (int tile = 0; tile < 4; ++tile) {
                union { _Float16 hh[2]; int u; } pk2;
                pk2.hh[0] = (_Float16)acc_bd[tile][reg];
                pk2.hh[1] = (_Float16)acc_bd[tile + 1][reg];
                union { int u; _Float16 hh[2]; } got;
                got.u = __shfl(pk2.u, srcl);
                const float bdv = (float)(lo ? got.hh[0] : got.hh[1]);
                float s = (acc_ac[tile][reg] + bdv) * 0.125f;
                if (tile == 3 && reg == 0 && isfix && kt == 7 && lane == 15)
                    s = (acc_ac[3][0] + fix) * 0.125f;   // (q=0, k=1023)
                const float wv = __expf(s);
                l_acc[reg] += wv;
                const int kk = tile * 16 + col;
                pw[rr * 64 + (((kk >> 3) ^ (rr & 7)) << 3) + (kk & 7)] = (__bf16)wv;
            }
        }
        // O += P~ . V
        #pragma unroll
        for (int hf = 0; hf < 2; ++hf) {
            bf16x8 afr = *(const bf16x8*)&pw[col * 64 + (((hf * 4 + grp) ^ swz) << 3)];
            #pragma unroll
            for (int tile = 0; tile < 4; ++tile) {
                const int rw = tile * 16 + col;
                bf16x8 bfr = *(const bf16x8*)&Vtlds[rw * 64 + ((hf * 4 + grp) ^ swz) * 8];
                acc_o[tile] = __builtin_amdgcn_mfma_f32_16x16x32_bf16(afr, bfr, acc_o[tile], 0, 0, 0);
            }
        }
    }
    // epilogue: unnormalized fp32 numerator + row-sum l
    #pragma unroll
    for (int reg = 0; reg < 4; ++reg) {
        const int qrow = q0 + w * 16 + grp * 4 + reg;
        float* orow = Opart + ((size_t)(kc * 4096 + b * 1024 + qrow)) * D_ + h * DK_;
        #pragma unroll
        for (int tile = 0; tile < 4; ++tile)
            orow[tile * 16 + col] = acc_o[tile][reg];
        float l = l_acc[reg];
        l += __shfl_xor(l, 1); l += __shfl_xor(l, 2);
        l += __shfl_xor(l, 4); l += __shfl_xor(l, 8);
        if (col == 0)
            lpart[((kc * 4 + b) * 8 + h) * 1024 + qrow] = l;
    }
}

// ---------------- merge the 2 k-chunks -> ctx bf16 ----------------
__global__ __launch_bounds__(256) void merge_kernel(const float* __restrict__ Op,
        const float* __restrict__ lp, __bf16* __restrict__ ch) {
    const int row = blockIdx.x;           // b*1024+s
    const int d0  = threadIdx.x * 2;
    const int h   = d0 >> 6;
    const int mlidx = ((row >> 10) * 8 + h) * 1024 + (row & 1023);
    const float inv = 1.0f / (lp[mlidx] + lp[mlidx + 32768]);
    const float2 o0 = *(const float2*)&Op[(size_t)row * D_ + d0];
    const float2 o1 = *(const float2*)&Op[(size_t)(row + 4096) * D_ + d0];
    bf16x2 r;
    r[0] = (__bf16)((o0.x + o1.x) * inv);
    r[1] = (__bf16)((o0.y + o1.y) * inv);
    *(bf16x2*)&ch[(size_t)row * D_ + d0] = r;
}

extern "C" void kernel_launch(void* const* d_in, const int* in_sizes, int n_in,
                              void* d_out, int out_size, void* d_ws, size_t ws_size,
                              hipStream_t stream) {
    (void)in_sizes; (void)n_in; (void)out_size; (void)ws_size;
    const float* inputs = (const float*)d_in[0];
    const float* Wq = (const float*)d_in[2];
    const float* bq = (const float*)d_in[3];
    const float* Wk = (const float*)d_in[4];
    const float* bk = (const float*)d_in[5];
    const float* Wv = (const float*)d_in[6];
    const float* bv = (const float*)d_in[7];
    const float* Wo = (const float*)d_in[8];
    const float* bo = (const float*)d_in[9];
    const float* Wp = (const float*)d_in[10];
    const float* pu = (const float*)d_in[11];
    const float* pv = (const float*)d_in[12];
    const float* gamma = (const float*)d_in[13];
    const float* beta  = (const float*)d_in[14];
    float* out = (float*)d_out;

    char* base = (char*)d_ws;
    // Overlap region (16 MB): xh (0-4MB) and peh (4-6MB) are dead before attn
    // writes Opart (fp32, 16 MB) which aliases them.
    __bf16* xh    = (__bf16*)(base);
    __bf16* peh   = (__bf16*)(base + 4 * MB_);
    float*  Opart = (float*)(base);
    char* p = base + 16 * MB_;
    __bf16* qb   = (__bf16*)p;  p += (size_t)4096 * 512 * 2;
    __bf16* kb   = (__bf16*)p;  p += (size_t)4096 * 512 * 2;
    __bf16* vt   = (__bf16*)p;  p += (size_t)4096 * 512 * 2;
    __bf16* pp   = (__bf16*)p;  p += (size_t)2056 * 512 * 2;
    __bf16* ctxh = (__bf16*)p;  p += (size_t)4096 * 512 * 2;
    __bf16* Wqkv = (__bf16*)p;  p += (size_t)1536 * 512 * 2;
    __bf16* Wpb  = (__bf16*)p;  p += (size_t)512 * 512 * 2;
    __bf16* Wob  = (__bf16*)p;  p += (size_t)512 * 512 * 2;
    float*  biasqkv = (float*)p; p += 1536 * 4;
    float*  lpart = (float*)p;

    prep_kernel<<<3328, 256, 0, stream>>>(inputs, gamma, beta, Wq, Wk, Wv, Wp, Wo,
                                          bq, bk, bv, xh, peh,
                                          Wqkv, Wpb, Wob, biasqkv);
    gemm_qkv_p<<<448, 256, 0, stream>>>(xh, Wqkv, biasqkv, peh, Wpb,
                                        qb, kb, vt, pp);
    attn_mfma<<<dim3(32, H_, B_), 256, 0, stream>>>(qb, kb, vt, pp, pu, pv,
                                                    Opart, lpart);
    merge_kernel<<<4096, 256, 0, stream>>>(Opart, lpart, ctxh);
    gemm_out64<<<256, 256, 0, stream>>>(ctxh, Wob, bo, out);
}